// Round 1
// baseline (492.022 us; speedup 1.0000x reference)
//
#include <hip/hip_runtime.h>
#include <math.h>

#define DUR 32
#define DIM 256
#define TT  528   // sum_{b} (32-b)

// ws layout (floats)
#define WS_BSUM 0       // [32]  sum of y per branch
#define WS_BSQ  32      // [32]  sum of y^2 per branch
#define WS_CY   64      // [528] sum_o y*ln_w per global t
#define WS_CW   592     // [528] sum_o ln_w
#define WS_CB   1120    // [528] sum_o ln_b
#define WS_S    1648    // [528] s = Wv @ c + 256*bv
#define WS_ZERO_FLOATS 1648

__device__ __forceinline__ float gelu_exact(float v) {
    return 0.5f * v * (1.0f + erff(v * 0.70710678118654752f));
}

// One block per (b, o). Thread i = input channel.
__global__ __launch_bounds__(256) void conv_kernel(
    const float* __restrict__ x, const float* __restrict__ W,
    const float* __restrict__ convb, const float* __restrict__ lnw,
    const float* __restrict__ lnb, float* ws)
{
    const int n  = threadIdx.x;
    const int bb = blockIdx.x >> 8;
    const int o  = blockIdx.x & 255;
    const int k  = bb + 1;     // kernel width (wave-uniform)
    const int L  = 32 - bb;    // output length (wave-uniform)

    // x column for channel n (x is (Dur, Dim) row-major -> coalesced)
    float xv[36];
#pragma unroll
    for (int tau = 0; tau < 32; ++tau) xv[tau] = x[tau * DIM + n];
    xv[32] = 0.f; xv[33] = 0.f; xv[34] = 0.f; xv[35] = 0.f;

    // weight row W[b,o,n,0:32]; only first k used, tail zeroed
    const float* wrow = W + ((size_t)(bb * DIM + o) * DIM + n) * (size_t)DUR;
    float wv[32];
    const int k4 = (k + 3) >> 2;
#pragma unroll
    for (int m = 0; m < 8; ++m) {
        if (m < k4) {   // uniform
            const float4 v = *(const float4*)(wrow + 4 * m);
            wv[4*m+0] = v.x; wv[4*m+1] = v.y; wv[4*m+2] = v.z; wv[4*m+3] = v.w;
        } else {
            wv[4*m+0] = 0.f; wv[4*m+1] = 0.f; wv[4*m+2] = 0.f; wv[4*m+3] = 0.f;
        }
    }
#pragma unroll
    for (int j = 0; j < 32; ++j) { if (j >= k) wv[j] = 0.f; }  // uniform per j

    float acc[32];
#pragma unroll
    for (int t = 0; t < 32; ++t) acc[t] = 0.f;

#pragma unroll
    for (int t = 0; t < 32; ++t) {
        if (t < L) {    // uniform
#pragma unroll
            for (int m = 0; m < 8; ++m) {
                if (4 * m < k) {  // uniform; wv tail is zero so padded lanes are no-ops
                    acc[t] = fmaf(xv[t + 4*m + 0], wv[4*m + 0], acc[t]);
                    acc[t] = fmaf(xv[t + 4*m + 1], wv[4*m + 1], acc[t]);
                    acc[t] = fmaf(xv[t + 4*m + 2], wv[4*m + 2], acc[t]);
                    acc[t] = fmaf(xv[t + 4*m + 3], wv[4*m + 3], acc[t]);
                }
            }
        }
    }

    // reduce over the 256 channels: wave shuffle, then LDS across 4 waves
    const int wave = n >> 6;
    const int lane = n & 63;
    __shared__ float red[128];

#pragma unroll
    for (int t = 0; t < 32; ++t) {
        if (t < L) {    // uniform
            float v = acc[t];
            v += __shfl_down(v, 32, 64);
            v += __shfl_down(v, 16, 64);
            v += __shfl_down(v, 8, 64);
            v += __shfl_down(v, 4, 64);
            v += __shfl_down(v, 2, 64);
            v += __shfl_down(v, 1, 64);
            acc[t] = v;  // valid on lane 0
        }
    }
    if (lane == 0) {
#pragma unroll
        for (int t = 0; t < 32; ++t) { if (t < L) red[wave * 32 + t] = acc[t]; }
    }
    __syncthreads();

    if (n < 64) {   // wave 0 handles epilogue
        float g = 0.f;
        if (n < L) {
            const float y = red[n] + red[32 + n] + red[64 + n] + red[96 + n]
                          + convb[bb * DIM + o];
            g = gelu_exact(y);
            const float lw = lnw[(size_t)(bb * DIM + o) * DUR + n];
            const float lb = lnb[(size_t)(bb * DIM + o) * DUR + n];
            const int tg = bb * 32 - (bb * (bb - 1)) / 2 + n;  // global concat pos
            atomicAdd(ws + WS_CY + tg, g * lw);
            atomicAdd(ws + WS_CW + tg, lw);
            atomicAdd(ws + WS_CB + tg, lb);
        }
        float s1 = g, s2 = g * g;
        s1 += __shfl_down(s1, 32, 64); s2 += __shfl_down(s2, 32, 64);
        s1 += __shfl_down(s1, 16, 64); s2 += __shfl_down(s2, 16, 64);
        s1 += __shfl_down(s1, 8, 64);  s2 += __shfl_down(s2, 8, 64);
        s1 += __shfl_down(s1, 4, 64);  s2 += __shfl_down(s2, 4, 64);
        s1 += __shfl_down(s1, 2, 64);  s2 += __shfl_down(s2, 2, 64);
        s1 += __shfl_down(s1, 1, 64);  s2 += __shfl_down(s2, 1, 64);
        if (n == 0) {
            atomicAdd(ws + WS_BSUM + bb, s1);
            atomicAdd(ws + WS_BSQ + bb, s2);
        }
    }
}

// c[t] from LN stats + colsums, then s = Wv @ c + 256*bv. 132 blocks x 4 rows.
__global__ __launch_bounds__(256) void proj1_kernel(
    float* ws, const float* __restrict__ in_proj_w,
    const float* __restrict__ in_proj_b)
{
    __shared__ float cc[TT];
    __shared__ float mu_s[32], r_s[32];
    __shared__ int map[TT];
    const int n = threadIdx.x;
    if (n < 32) {
        const int Lb = 32 - n;
        const float cnt = 256.f * (float)Lb;
        const float mu = ws[WS_BSUM + n] / cnt;
        const float var = ws[WS_BSQ + n] / cnt - mu * mu;
        mu_s[n] = mu;
        r_s[n] = rsqrtf(var + 1e-5f);
        const int off = n * 32 - (n * (n - 1)) / 2;
        for (int t = 0; t < Lb; ++t) map[off + t] = n;
    }
    __syncthreads();
    for (int t = n; t < TT; t += 256) {
        const int b = map[t];
        cc[t] = (ws[WS_CY + t] - mu_s[b] * ws[WS_CW + t]) * r_s[b] + ws[WS_CB + t];
    }
    __syncthreads();
    const int wave = n >> 6, lane = n & 63;
    const int row = blockIdx.x * 4 + wave;   // t'
    const float* Wr = in_proj_w + (size_t)(2 * TT + row) * TT;
    float a = 0.f;
    for (int t = lane; t < TT; t += 64) a = fmaf(Wr[t], cc[t], a);
    a += __shfl_down(a, 32, 64);
    a += __shfl_down(a, 16, 64);
    a += __shfl_down(a, 8, 64);
    a += __shfl_down(a, 4, 64);
    a += __shfl_down(a, 2, 64);
    a += __shfl_down(a, 1, 64);
    if (lane == 0) ws[WS_S + row] = a + 256.f * in_proj_b[2 * TT + row];
}

// S[u] = out_proj_w[u,:] . s + 256*opb[u] for u = w*128 + j (j<32); out = mean_j
__global__ __launch_bounds__(256) void proj2_kernel(
    const float* __restrict__ ws, const float* __restrict__ out_proj_w,
    const float* __restrict__ out_proj_b, float* __restrict__ out)
{
    __shared__ float sv[TT];
    __shared__ float Sacc[32];
    __shared__ float meanv;
    const int n = threadIdx.x;
    for (int t = n; t < TT; t += 256) sv[t] = ws[WS_S + t];
    __syncthreads();
    const int wave = n >> 6, lane = n & 63;
#pragma unroll
    for (int jj = 0; jj < 8; ++jj) {
        const int j = wave * 8 + jj;
        const int u = blockIdx.x * 128 + j;
        const float* Or = out_proj_w + (size_t)u * TT;
        float a = 0.f;
        for (int t = lane; t < TT; t += 64) a = fmaf(Or[t], sv[t], a);
        a += __shfl_down(a, 32, 64);
        a += __shfl_down(a, 16, 64);
        a += __shfl_down(a, 8, 64);
        a += __shfl_down(a, 4, 64);
        a += __shfl_down(a, 2, 64);
        a += __shfl_down(a, 1, 64);
        if (lane == 0) Sacc[j] = a + 256.f * out_proj_b[u];
    }
    __syncthreads();
    if (n == 0) {
        float m = 0.f;
        for (int j = 0; j < 32; ++j) m += Sacc[j];
        meanv = m * (1.0f / 32.0f);
    }
    __syncthreads();
    out[blockIdx.x * 256 + n] = meanv;  // same value for all 256 dims
}

extern "C" void kernel_launch(void* const* d_in, const int* in_sizes, int n_in,
                              void* d_out, int out_size, void* d_ws, size_t ws_size,
                              hipStream_t stream)
{
    const float* x   = (const float*)d_in[0];
    const float* W   = (const float*)d_in[1];
    const float* cb  = (const float*)d_in[2];
    const float* lnw = (const float*)d_in[3];
    const float* lnb = (const float*)d_in[4];
    const float* ipw = (const float*)d_in[5];
    const float* ipb = (const float*)d_in[6];
    const float* opw = (const float*)d_in[7];
    const float* opb = (const float*)d_in[8];
    float* ws  = (float*)d_ws;
    float* out = (float*)d_out;

    hipMemsetAsync(ws, 0, WS_ZERO_FLOATS * sizeof(float), stream);
    conv_kernel<<<32 * 256, 256, 0, stream>>>(x, W, cb, lnw, lnb, ws);
    proj1_kernel<<<132, 256, 0, stream>>>(ws, ipw, ipb);
    proj2_kernel<<<4, 256, 0, stream>>>(ws, opw, opb, out);
}